// Round 6
// baseline (207.412 us; speedup 1.0000x reference)
//
#include <hip/hip_runtime.h>

#define THREADS 256
#define NPMAX   256
#define NCELLS  4096   // 16^3 Morton grid over [-4,4], cell width 0.5

// ---- ws layout ----
// parts   : 2*NPMAX float4   @ 0       (8 KB)
// dcount  : int              @ 8192
// hist    : NCELLS u32       @ 16384   (16 KB)  -- memset to 0 each call
// cursor  : NCELLS u32       @ 32768   (16 KB)
// cellid  : N u32            @ 1 MB    (1 MB)
// scoord  : N float4         @ 8 MB    (4 MB)

__device__ inline unsigned spread4(unsigned v) {   // 4 bits -> every 3rd bit
    return (v & 1u) | ((v & 2u) << 2) | ((v & 4u) << 4) | ((v & 8u) << 6);
}
__device__ inline unsigned cellOf(float x, float y, float z) {
    int cx = (int)floorf((x + 4.0f) * 2.0f);
    int cy = (int)floorf((y + 4.0f) * 2.0f);
    int cz = (int)floorf((z + 4.0f) * 2.0f);
    cx = min(max(cx, 0), 15); cy = min(max(cy, 0), 15); cz = min(max(cz, 0), 15);
    return spread4((unsigned)cx) | (spread4((unsigned)cy) << 1) | (spread4((unsigned)cz) << 2);
}

// ---------------------------------------------------------------------------
// K1: particle prep (block 0 only) + coord cell-id & histogram (all blocks)
// parts: pa = {px,py,pz, -log2e/(2r^2)}, pb = {A*dx,A*dy,A*dz, 9r^2}
// ---------------------------------------------------------------------------
__global__ __launch_bounds__(THREADS) void k_prep_hist(
        const float* __restrict__ coord,
        const float* __restrict__ ppos,  const float* __restrict__ pdir,
        const float* __restrict__ pint,  const float* __restrict__ iraw,
        const float* __restrict__ rad,   const int* __restrict__ tmask,
        const int* __restrict__ tidxp,   int N, int P, int T,
        float4* __restrict__ parts, int* __restrict__ dcount,
        unsigned* __restrict__ hist, unsigned* __restrict__ cellid) {
    const int tid  = threadIdx.x;
    const int lane = tid & 63;
    const int wid  = tid >> 6;

    if (blockIdx.x == 0) {
        __shared__ int wtot[THREADS / 64];
        const int t = *tidxp;
        bool active = false;
        float4 a, b;
        if (tid < P) {
            const int p = tid;
            float m  = (float)tmask[p * T + t];
            float cl = fminf(fmaxf(iraw[p], 0.0f), 10.0f);
            float w  = sqrtf(cl + 1e-8f) * pint[p * T + t] * m;
            float r  = fmaxf(0.2f * (0.5f * rad[p] + 1.0f), 0.0f);
            active   = (w != 0.0f) && (r > 0.0f);
            if (active) {
                const float* pp = ppos + (size_t)(p * T + t) * 3;
                const float* pd = pdir + (size_t)(p * T + t) * 3;
                float A = w / (r * r * r * 40000.0f);
                a = make_float4(pp[0], pp[1], pp[2], -1.442695040888963f / (2.0f * r * r));
                b = make_float4(A * pd[0], A * pd[1], A * pd[2], 9.0f * r * r);
            }
        }
        unsigned long long bm = __ballot(active);
        int pre = __popcll(bm & ((1ull << lane) - 1ull));
        if (lane == 0) wtot[wid] = __popcll(bm);
        __syncthreads();
        int off = 0, tot = 0;
        #pragma unroll
        for (int w2 = 0; w2 < THREADS / 64; ++w2) {
            int c = wtot[w2];
            if (w2 < wid) off += c;
            tot += c;
        }
        if (active) {
            int pos = off + pre;
            parts[2 * pos]     = a;
            parts[2 * pos + 1] = b;
        }
        if (tid == 0) *dcount = tot;
    }

    const int gid = blockIdx.x * THREADS + tid;
    if (gid < N) {
        float x = coord[3 * gid], y = coord[3 * gid + 1], z = coord[3 * gid + 2];
        unsigned c = cellOf(x, y, z);
        cellid[gid] = c;
        atomicAdd(&hist[c], 1u);
    }
}

// ---------------------------------------------------------------------------
// K2: exclusive scan of hist -> cursor (single wave: 64 lanes x 64 cells)
// ---------------------------------------------------------------------------
__global__ void k_scan(const unsigned* __restrict__ hist,
                       unsigned* __restrict__ cursor) {
    const int l = threadIdx.x;          // 0..63
    const int base = l * 64;
    unsigned s = 0;
    #pragma unroll 8
    for (int i = 0; i < 64; ++i) s += hist[base + i];
    unsigned run = s;
    #pragma unroll
    for (int d = 1; d < 64; d <<= 1) {
        unsigned t = __shfl_up(run, d);
        if (l >= d) run += t;
    }
    unsigned acc = run - s;             // exclusive offset for this lane's span
    #pragma unroll 8
    for (int i = 0; i < 64; ++i) {
        cursor[base + i] = acc;
        acc += hist[base + i];
    }
}

// ---------------------------------------------------------------------------
// K3: scatter coords into cell-sorted order; .w carries the original index
// ---------------------------------------------------------------------------
__global__ __launch_bounds__(THREADS) void k_scatter(
        const float* __restrict__ coord, const unsigned* __restrict__ cellid,
        unsigned* __restrict__ cursor, float4* __restrict__ scoord, int N) {
    const int gid = blockIdx.x * THREADS + threadIdx.x;
    if (gid < N) {
        unsigned c = cellid[gid];
        unsigned slot = atomicAdd(&cursor[c], 1u);
        scoord[slot] = make_float4(coord[3 * gid], coord[3 * gid + 1],
                                   coord[3 * gid + 2], __int_as_float(gid));
    }
}

// ---------------------------------------------------------------------------
// K4: main. Per block: bbox of its 256 sorted coords -> conservative AABB
// particle cull (excluded particles contribute exactly 0) -> inner loop over
// compacted candidates with per-lane early-out. Scatter-write to out[orig].
// ---------------------------------------------------------------------------
__global__ __launch_bounds__(THREADS) void k_main(
        const float4* __restrict__ scoord, const float4* __restrict__ parts,
        const int* __restrict__ dcount, float* __restrict__ out, int N) {
    __shared__ float4 ca[NPMAX], cb[NPMAX];
    __shared__ float  wred[THREADS / 64][6];
    __shared__ float  bmin[3], bmax[3];
    __shared__ int    wtot[THREADS / 64];
    __shared__ int    s_ccnt;

    const int tid  = threadIdx.x;
    const int lane = tid & 63;
    const int wid  = tid >> 6;
    const int gid  = blockIdx.x * THREADS + tid;
    const bool valid = (gid < N);

    float4 sc = scoord[valid ? gid : (N - 1)];
    const float cx = sc.x, cy = sc.y, cz = sc.z;
    const int orig = __float_as_int(sc.w);

    // ---- block bbox: wave shuffle-reduce, then cross-wave via LDS ----
    float mnx = cx, mxx = cx, mny = cy, mxy = cy, mnz = cz, mxz = cz;
    #pragma unroll
    for (int d = 32; d >= 1; d >>= 1) {
        mnx = fminf(mnx, __shfl_xor(mnx, d)); mxx = fmaxf(mxx, __shfl_xor(mxx, d));
        mny = fminf(mny, __shfl_xor(mny, d)); mxy = fmaxf(mxy, __shfl_xor(mxy, d));
        mnz = fminf(mnz, __shfl_xor(mnz, d)); mxz = fmaxf(mxz, __shfl_xor(mxz, d));
    }
    if (lane == 0) {
        wred[wid][0] = mnx; wred[wid][1] = mxx; wred[wid][2] = mny;
        wred[wid][3] = mxy; wred[wid][4] = mnz; wred[wid][5] = mxz;
    }
    __syncthreads();
    if (tid == 0) {
        float a0 = wred[0][0], a1 = wred[0][1], a2 = wred[0][2];
        float a3 = wred[0][3], a4 = wred[0][4], a5 = wred[0][5];
        #pragma unroll
        for (int w2 = 1; w2 < THREADS / 64; ++w2) {
            a0 = fminf(a0, wred[w2][0]); a1 = fmaxf(a1, wred[w2][1]);
            a2 = fminf(a2, wred[w2][2]); a3 = fmaxf(a3, wred[w2][3]);
            a4 = fminf(a4, wred[w2][4]); a5 = fmaxf(a5, wred[w2][5]);
        }
        bmin[0] = a0; bmax[0] = a1; bmin[1] = a2;
        bmax[1] = a3; bmin[2] = a4; bmax[2] = a5;
    }
    const int cnt = __builtin_amdgcn_readfirstlane(*dcount);
    __syncthreads();

    // ---- conservative candidate cull + order-preserving compaction ----
    bool cand = false;
    float4 a, b;
    if (tid < cnt) {
        a = parts[2 * tid];
        b = parts[2 * tid + 1];
        float qx = fminf(fmaxf(a.x, bmin[0]), bmax[0]) - a.x;
        float qy = fminf(fmaxf(a.y, bmin[1]), bmax[1]) - a.y;
        float qz = fminf(fmaxf(a.z, bmin[2]), bmax[2]) - a.z;
        float d2b = fmaf(qx, qx, fmaf(qy, qy, qz * qz));
        cand = d2b < b.w;     // excluded => every lane's d2 >= cut => exact 0
    }
    unsigned long long bm = __ballot(cand);
    int pre = __popcll(bm & ((1ull << lane) - 1ull));
    if (lane == 0) wtot[wid] = __popcll(bm);
    __syncthreads();
    int off = 0, tot = 0;
    #pragma unroll
    for (int w2 = 0; w2 < THREADS / 64; ++w2) {
        int c = wtot[w2];
        if (w2 < wid) off += c;
        tot += c;
    }
    if (cand) {
        int pos = off + pre;
        ca[pos] = a;
        cb[pos] = b;
    }
    if (tid == 0) s_ccnt = tot;
    __syncthreads();
    const int C = s_ccnt;

    // ---- inner loop over candidates ----
    float ax = 0.f, ay = 0.f, az = 0.f;
    #pragma unroll 2
    for (int c = 0; c < C; ++c) {
        const float4 pa = ca[c];
        const float4 pb = cb[c];
        float lx = pa.x - cx, ly = pa.y - cy, lz = pa.z - cz;
        float d2 = fmaf(lx, lx, fmaf(ly, ly, lz * lz));
        if (d2 < pb.w) {
            float s = __builtin_amdgcn_exp2f(d2 * pa.w) * __builtin_amdgcn_rsqf(d2);
            float crx = fmaf(ly, pb.z, -(lz * pb.y));
            float cry = fmaf(lz, pb.x, -(lx * pb.z));
            float crz = fmaf(lx, pb.y, -(ly * pb.x));
            ax = fmaf(s, crx, ax);
            ay = fmaf(s, cry, ay);
            az = fmaf(s, crz, az);
        }
    }

    if (valid) {
        out[3 * orig]     = ax;
        out[3 * orig + 1] = ay;
        out[3 * orig + 2] = az;
    }
}

extern "C" void kernel_launch(void* const* d_in, const int* in_sizes, int n_in,
                              void* d_out, int out_size, void* d_ws, size_t ws_size,
                              hipStream_t stream) {
    const float* coord = (const float*)d_in[0];
    const float* ppos  = (const float*)d_in[1];
    const float* pdir  = (const float*)d_in[2];
    const float* pint  = (const float*)d_in[3];
    const float* iraw  = (const float*)d_in[4];
    const float* rad   = (const float*)d_in[5];
    const int*   tmask = (const int*)d_in[6];
    const int*   tidx  = (const int*)d_in[7];
    float* out = (float*)d_out;

    const int N = in_sizes[0] / 3;        // 262144 coords
    const int P = in_sizes[4];            // 256 particles
    const int T = in_sizes[3] / P;        // 8 time steps

    char* ws = (char*)d_ws;
    float4*   parts  = (float4*)ws;
    int*      dcount = (int*)(ws + 8192);
    unsigned* hist   = (unsigned*)(ws + 16384);
    unsigned* cursor = (unsigned*)(ws + 32768);
    unsigned* cellid = (unsigned*)(ws + (1 << 20));
    float4*   scoord = (float4*)(ws + (8 << 20));

    hipMemsetAsync(hist, 0, NCELLS * sizeof(unsigned), stream);

    const int blocks = (N + THREADS - 1) / THREADS;
    hipLaunchKernelGGL(k_prep_hist, dim3(blocks), dim3(THREADS), 0, stream,
                       coord, ppos, pdir, pint, iraw, rad, tmask, tidx,
                       N, P, T, parts, dcount, hist, cellid);
    hipLaunchKernelGGL(k_scan, dim3(1), dim3(64), 0, stream, hist, cursor);
    hipLaunchKernelGGL(k_scatter, dim3(blocks), dim3(THREADS), 0, stream,
                       coord, cellid, cursor, scoord, N);
    hipLaunchKernelGGL(k_main, dim3(blocks), dim3(THREADS), 0, stream,
                       scoord, parts, dcount, out, N);
}

// Round 8
// 32.793 us; speedup vs baseline: 6.3248x; 6.3248x over previous
//
#include <hip/hip_runtime.h>

#define THREADS 256
#define NPMAX   260   // 256 + pad room

typedef __attribute__((ext_vector_type(8))) float f32x8;

// One particle = 32 B = {px,py,pz, -log2e/(2r^2), A*dx,A*dy,A*dz, 9r^2}
// loaded broadcast into SGPRs via s_load_dwordx8.
#define SLOAD8(dst, base, imm) \
    asm volatile("s_load_dwordx8 %0, %1, " imm : "=s"(dst) : "s"(base))

// Every VALU op below reads at most one SGPR operand (rest VGPR).
#define INTER(V)                                                          \
    {                                                                     \
        float lx = V[0] - cx, ly = V[1] - cy, lz = V[2] - cz;             \
        float d2 = fmaf(lx, lx, fmaf(ly, ly, lz * lz));                   \
        float s  = __builtin_amdgcn_exp2f(d2 * V[3]) *                    \
                   __builtin_amdgcn_rsqf(d2);                             \
        s = (d2 < V[7]) ? s : 0.0f;                                       \
        ax = fmaf(s, fmaf(ly, V[6], -(lz * V[5])), ax);                   \
        ay = fmaf(s, fmaf(lz, V[4], -(lx * V[6])), ay);                   \
        az = fmaf(s, fmaf(lx, V[5], -(ly * V[4])), az);                   \
    }

// ---------------------------------------------------------------------------
// Prep (1 block): per-particle constants at time_idx, ballot-compacted
// (deterministic stable order) into d_ws, ZERO-PADDED to a multiple of 4.
// Pad entries have pb.w = 0 -> (d2 < 0) never true -> exact 0 contribution.
// ---------------------------------------------------------------------------
__global__ __launch_bounds__(THREADS) void vortex_prep(
        const float* __restrict__ ppos,
        const float* __restrict__ pdir,
        const float* __restrict__ pint,
        const float* __restrict__ iraw,
        const float* __restrict__ rad,
        const int*   __restrict__ tmask,
        const int*   __restrict__ tidxp,
        int P, int T,
        float4* __restrict__ parts,
        int*    __restrict__ dcount) {
    __shared__ int wtot[THREADS / 64];
    const int tid  = threadIdx.x;
    const int lane = tid & 63;
    const int wid  = tid >> 6;
    const int t = *tidxp;

    bool active = false;
    float4 a, b;
    if (tid < P) {
        const int p = tid;
        float m  = (float)tmask[p * T + t];
        float cl = fminf(fmaxf(iraw[p], 0.0f), 10.0f);
        float w  = sqrtf(cl + 1e-8f) * pint[p * T + t] * m;
        float r  = fmaxf(0.2f * (0.5f * rad[p] + 1.0f), 0.0f);
        active   = (w != 0.0f) && (r > 0.0f);
        if (active) {
            const float* pp = ppos + (size_t)(p * T + t) * 3;
            const float* pd = pdir + (size_t)(p * T + t) * 3;
            float A = w / (r * r * r * 40000.0f);
            a = make_float4(pp[0], pp[1], pp[2], -1.442695040888963f / (2.0f * r * r));
            b = make_float4(A * pd[0], A * pd[1], A * pd[2], 9.0f * r * r);
        }
    }
    unsigned long long bm = __ballot(active);
    int pre = __popcll(bm & ((1ull << lane) - 1ull));
    if (lane == 0) wtot[wid] = __popcll(bm);
    __syncthreads();
    int off = 0, tot = 0;
    #pragma unroll
    for (int w2 = 0; w2 < THREADS / 64; ++w2) {
        int c = wtot[w2];
        if (w2 < wid) off += c;
        tot += c;
    }
    if (active) {
        int pos = off + pre;
        parts[2 * pos]     = a;
        parts[2 * pos + 1] = b;
    }
    const int tot_pad = (tot + 3) & ~3;
    if (tid >= tot && tid < tot_pad) {
        parts[2 * tid]     = make_float4(0.f, 0.f, 0.f, 0.f);
        parts[2 * tid + 1] = make_float4(0.f, 0.f, 0.f, 0.f);
    }
    if (tid == 0) *dcount = tot_pad;
}

// ---------------------------------------------------------------------------
// Main: 1 coord/thread, 1024 blocks (4 waves/SIMD). Hot loop: batches of 4
// particles via s_load_dwordx8 into SGPRs, ONE safe s_waitcnt lgkmcnt(0)
// (SMEM returns out-of-order -> counted waits are invalid), sched_barrier to
// pin VALU after the wait. No LDS, no vector memory in the loop.
// ---------------------------------------------------------------------------
__global__ __launch_bounds__(THREADS) void vortex_main(
        const float* __restrict__ coord,
        const float* __restrict__ parts,
        const int*   __restrict__ dcount,
        float*       __restrict__ out,
        int N) {
    const int i0 = blockIdx.x * THREADS + threadIdx.x;
    const bool v0 = (i0 < N);
    float cx = 0.f, cy = 0.f, cz = 0.f;
    if (v0) { cx = coord[3 * i0]; cy = coord[3 * i0 + 1]; cz = coord[3 * i0 + 2]; }

    const int cnt = __builtin_amdgcn_readfirstlane(*dcount);   // multiple of 4

    float ax = 0.f, ay = 0.f, az = 0.f;

    const float* bp = parts;
    for (int p = 0; p < cnt; p += 4) {
        f32x8 V0, V1, V2, V3;
        SLOAD8(V0, bp, "0x00");
        SLOAD8(V1, bp, "0x20");
        SLOAD8(V2, bp, "0x40");
        SLOAD8(V3, bp, "0x60");
        asm volatile("s_waitcnt lgkmcnt(0)" ::: "memory");
        __builtin_amdgcn_sched_barrier(0);
        INTER(V0);
        INTER(V1);
        INTER(V2);
        INTER(V3);
        bp += 32;   // 4 particles * 8 floats
    }

    if (v0) { out[3 * i0] = ax; out[3 * i0 + 1] = ay; out[3 * i0 + 2] = az; }
}

extern "C" void kernel_launch(void* const* d_in, const int* in_sizes, int n_in,
                              void* d_out, int out_size, void* d_ws, size_t ws_size,
                              hipStream_t stream) {
    const float* coord = (const float*)d_in[0];
    const float* ppos  = (const float*)d_in[1];
    const float* pdir  = (const float*)d_in[2];
    const float* pint  = (const float*)d_in[3];
    const float* iraw  = (const float*)d_in[4];
    const float* rad   = (const float*)d_in[5];
    const int*   tmask = (const int*)d_in[6];
    const int*   tidx  = (const int*)d_in[7];
    float* out = (float*)d_out;

    const int N = in_sizes[0] / 3;        // 262144 coords
    const int P = in_sizes[4];            // 256 particles
    const int T = in_sizes[3] / P;        // 8 time steps

    float4* parts = (float4*)d_ws;
    int* dcount   = (int*)((char*)d_ws + (size_t)2 * NPMAX * sizeof(float4));

    hipLaunchKernelGGL(vortex_prep, dim3(1), dim3(THREADS), 0, stream,
                       ppos, pdir, pint, iraw, rad, tmask, tidx, P, T, parts, dcount);

    const int blocks = (N + THREADS - 1) / THREADS;
    hipLaunchKernelGGL(vortex_main, dim3(blocks), dim3(THREADS), 0, stream,
                       coord, (const float*)parts, dcount, out, N);
}